// Round 1
// baseline (490.741 us; speedup 1.0000x reference)
//
#include <hip/hip_runtime.h>
#include <math.h>

#define NB 4
#define NC 12
#define NM 2
#define NN 320
#define NHW (NN*NN)
#define NBC (NB*NC)
#define CG_TOL 1e-6f
#define NITER 10
#define CBLK 400   // blocks per batch for combine/update kernels (102400/256)

#define PI_F     3.14159265358979323846f
#define TWO_PI_F 6.28318530717958647692f

typedef float2 c32;

__device__ __forceinline__ c32 cmul(c32 a, c32 b){ return make_float2(a.x*b.x - a.y*b.y, a.x*b.y + a.y*b.x); }
__device__ __forceinline__ c32 cmulj(c32 a, c32 b){ return make_float2(a.x*b.x + a.y*b.y, a.x*b.y - a.y*b.x); } // conj(a)*b
__device__ __forceinline__ c32 cadd(c32 a, c32 b){ return make_float2(a.x+b.x, a.y+b.y); }
__device__ __forceinline__ c32 csub(c32 a, c32 b){ return make_float2(a.x-b.x, a.y-b.y); }
__device__ __forceinline__ c32 cscale(c32 a, float s){ return make_float2(a.x*s, a.y*s); }

__device__ __forceinline__ float wave_reduce_f(float v) {
  #pragma unroll
  for (int off = 32; off >= 1; off >>= 1) v += __shfl_xor(v, off, 64);
  return v;
}
__device__ __forceinline__ c32 wave_reduce_c(c32 v) {
  #pragma unroll
  for (int off = 32; off >= 1; off >>= 1) {
    v.x += __shfl_xor(v.x, off, 64);
    v.y += __shfl_xor(v.y, off, 64);
  }
  return v;
}

// 320-point FFT: input A[j] = x[64*j + lane] (j=0..4) distributed over one wave.
// Output: A[k1] at lane l holds X[k1 + 5*rev6(l)].  DIR=-1 fwd, +1 inv. Unnormalized.
template<int DIR>
__device__ __forceinline__ void fft320(c32 A[5], int lane) {
  // radix-5 across the 5 registers: A[k1] = sum_j v[j] * cis(DIR*2pi*j*k1/5)
  c32 w5[5];
  w5[0] = make_float2(1.f, 0.f);
  #pragma unroll
  for (int r2 = 1; r2 < 5; ++r2) {
    float s, c;
    sincosf((float)DIR * TWO_PI_F * (float)r2 * 0.2f, &s, &c);
    w5[r2] = make_float2(c, s);
  }
  c32 v0 = A[0], v1 = A[1], v2 = A[2], v3 = A[3], v4 = A[4];
  #pragma unroll
  for (int k1 = 0; k1 < 5; ++k1) {
    c32 acc = v0;
    acc = cadd(acc, cmul(v1, w5[(1*k1)%5]));
    acc = cadd(acc, cmul(v2, w5[(2*k1)%5]));
    acc = cadd(acc, cmul(v3, w5[(3*k1)%5]));
    acc = cadd(acc, cmul(v4, w5[(4*k1)%5]));
    A[k1] = acc;
  }
  // CT twiddle W_320^{lane*k1}
  {
    float s, c;
    sincosf((float)DIR * TWO_PI_F * (float)lane / 320.f, &s, &c);
    c32 t1 = make_float2(c, s);
    c32 t2 = cmul(t1, t1);
    c32 t3 = cmul(t2, t1);
    c32 t4 = cmul(t2, t2);
    A[1] = cmul(A[1], t1);
    A[2] = cmul(A[2], t2);
    A[3] = cmul(A[3], t3);
    A[4] = cmul(A[4], t4);
  }
  // 64-point radix-2 DIF across lanes via shfl_xor; output bit-reversed over lanes
  #pragma unroll
  for (int s = 0; s < 6; ++s) {
    const int m = 32 >> s;
    const int j = lane & (m - 1);
    float ss, cc;
    sincosf((float)DIR * PI_F * (float)j / (float)m, &ss, &cc);
    const c32 w = make_float2(cc, ss);
    const bool up = (lane & m) != 0;
    #pragma unroll
    for (int k1 = 0; k1 < 5; ++k1) {
      c32 o;
      o.x = __shfl_xor(A[k1].x, m, 64);
      o.y = __shfl_xor(A[k1].y, m, 64);
      c32 lo = cadd(A[k1], o);
      c32 hi = cmul(csub(o, A[k1]), w);
      A[k1] = up ? hi : lo;
    }
  }
}

// One batched-1D-FFT pass over the contiguous (last) dim of a (NBC, NN, NN) array,
// writing the result transposed: out[bc][u][row] = FFT_row(in[bc][row][:])[u].
// IN_MODE: 0 = read in[]; 1 = combine sum_m p*sm on the fly (row = h); 2 = in[]*mask.
// OUT_MASK: 1 = multiply by mask at the output (natural (B,C,H,W) index).
template<int DIR, int IN_MODE, int OUT_MASK>
__global__ __launch_bounds__(256)
void fft_pass(const c32* __restrict__ in, c32* __restrict__ out,
              const c32* __restrict__ pvec, const c32* __restrict__ smaps,
              const float* __restrict__ mask, const float* __restrict__ flag)
{
  if (flag != nullptr && flag[0] == 0.f) return;
  __shared__ c32 tile[8][NN + 1];
  const int tid  = threadIdx.x;
  const int lane = tid & 63;
  const int wv   = tid >> 6;
  const int bc   = blockIdx.y;
  const int r0   = blockIdx.x * 8;

  #pragma unroll
  for (int rep = 0; rep < 2; ++rep) {
    const int ri  = wv * 2 + rep;
    const int row = r0 + ri;
    c32 A[5];
    if constexpr (IN_MODE == 0) {
      #pragma unroll
      for (int j = 0; j < 5; ++j)
        A[j] = in[((size_t)bc * NN + row) * NN + lane + 64*j];
    } else if constexpr (IN_MODE == 1) {
      const int b = bc / NC;
      const int c = bc % NC;
      #pragma unroll
      for (int j = 0; j < 5; ++j) {
        const int col = lane + 64*j;
        const size_t hw = (size_t)row * NN + col;
        c32 p0 = pvec[(size_t)(b*NM + 0) * NHW + hw];
        c32 p1 = pvec[(size_t)(b*NM + 1) * NHW + hw];
        c32 s0 = smaps[(size_t)((b*NC + c)*NM + 0) * NHW + hw];
        c32 s1 = smaps[(size_t)((b*NC + c)*NM + 1) * NHW + hw];
        A[j] = cadd(cmul(p0, s0), cmul(p1, s1));
      }
    } else {
      #pragma unroll
      for (int j = 0; j < 5; ++j) {
        const size_t idx = ((size_t)bc * NN + row) * NN + lane + 64*j;
        A[j] = cscale(in[idx], mask[idx]);
      }
    }
    fft320<DIR>(A, lane);
    const int rv6 = __brev((unsigned)lane) >> 26;
    #pragma unroll
    for (int k1 = 0; k1 < 5; ++k1)
      tile[ri][k1 + 5*rv6] = A[k1];
  }
  __syncthreads();
  // transposed write: out[bc][u][r0+d]
  #pragma unroll
  for (int it = 0; it < 10; ++it) {
    const int idx = it * 256 + tid;
    const int u = idx >> 3;
    const int d = idx & 7;
    c32 val = tile[d][u];
    const size_t oidx = ((size_t)bc * NN + u) * NN + (r0 + d);
    if constexpr (OUT_MASK == 1) val = cscale(val, mask[oidx]);
    out[oidx] = val;
  }
}

// x0 = (lam/NN) * sum_c conj(sm)*img + z ; x=0, r=p=x0 ; partial sum |x0|^2
__global__ __launch_bounds__(256)
void init_combine(const c32* __restrict__ img, const c32* __restrict__ smaps,
                  const c32* __restrict__ z, c32* __restrict__ x,
                  c32* __restrict__ r, c32* __restrict__ p,
                  const float* __restrict__ lam, float* __restrict__ part)
{
  const int b  = blockIdx.y;
  const int hw = blockIdx.x * 256 + threadIdx.x;
  const float l0 = lam[0] * (1.f / (float)NN);
  c32 a0 = make_float2(0.f,0.f), a1 = make_float2(0.f,0.f);
  #pragma unroll
  for (int c = 0; c < NC; ++c) {
    c32 iv = img[(size_t)(b*NC + c) * NHW + hw];
    c32 s0 = smaps[(size_t)((b*NC + c)*NM + 0) * NHW + hw];
    c32 s1 = smaps[(size_t)((b*NC + c)*NM + 1) * NHW + hw];
    a0 = cadd(a0, cmulj(s0, iv));
    a1 = cadd(a1, cmulj(s1, iv));
  }
  const size_t i0 = (size_t)(b*NM + 0) * NHW + hw;
  const size_t i1 = (size_t)(b*NM + 1) * NHW + hw;
  c32 x00 = cadd(cscale(a0, l0), z[i0]);
  c32 x01 = cadd(cscale(a1, l0), z[i1]);
  x[i0] = make_float2(0.f,0.f); x[i1] = make_float2(0.f,0.f);
  r[i0] = x00; r[i1] = x01;
  p[i0] = x00; p[i1] = x01;
  float acc = x00.x*x00.x + x00.y*x00.y + x01.x*x01.x + x01.y*x01.y;
  acc = wave_reduce_f(acc);
  __shared__ float sred[4];
  const int lane = threadIdx.x & 63, wv = threadIdx.x >> 6;
  if (lane == 0) sred[wv] = acc;
  __syncthreads();
  if (threadIdx.x == 0) part[b*CBLK + blockIdx.x] = sred[0]+sred[1]+sred[2]+sred[3];
}

__global__ void reduce_init(const float* __restrict__ part, float* __restrict__ x0x0,
                            float* __restrict__ rr0, float* __restrict__ flags)
{
  const int lane = threadIdx.x & 63;
  const int b = threadIdx.x >> 6;
  float s = 0.f;
  for (int j = lane; j < CBLK; j += 64) s += part[b*CBLK + j];
  s = wave_reduce_f(s);
  if (lane == 0) { x0x0[b] = s; rr0[b] = s; }
  if (threadIdx.x == 0) flags[0] = 1.f;  // rr0/x0x0 == 1 > tol always
}

// q = (lam/NHW) * sum_c conj(sm)*img + p ; partial pq = sum p*conj(q)
__global__ __launch_bounds__(256)
void q_combine(const c32* __restrict__ img, const c32* __restrict__ smaps,
               const c32* __restrict__ p, c32* __restrict__ q,
               const float* __restrict__ lam, const float* __restrict__ flag,
               c32* __restrict__ pqpart)
{
  if (flag[0] == 0.f) return;
  const int b  = blockIdx.y;
  const int hw = blockIdx.x * 256 + threadIdx.x;
  const float lq = lam[0] * (1.f / (float)NHW);
  c32 a0 = make_float2(0.f,0.f), a1 = make_float2(0.f,0.f);
  #pragma unroll
  for (int c = 0; c < NC; ++c) {
    c32 iv = img[(size_t)(b*NC + c) * NHW + hw];
    c32 s0 = smaps[(size_t)((b*NC + c)*NM + 0) * NHW + hw];
    c32 s1 = smaps[(size_t)((b*NC + c)*NM + 1) * NHW + hw];
    a0 = cadd(a0, cmulj(s0, iv));
    a1 = cadd(a1, cmulj(s1, iv));
  }
  const size_t i0 = (size_t)(b*NM + 0) * NHW + hw;
  const size_t i1 = (size_t)(b*NM + 1) * NHW + hw;
  c32 p0 = p[i0], p1 = p[i1];
  c32 q0 = cadd(cscale(a0, lq), p0);
  c32 q1 = cadd(cscale(a1, lq), p1);
  q[i0] = q0; q[i1] = q1;
  c32 s = cadd(cmulj(q0, p0), cmulj(q1, p1));  // p*conj(q) = conj(q)*p
  s = wave_reduce_c(s);
  __shared__ c32 sred[4];
  const int lane = threadIdx.x & 63, wv = threadIdx.x >> 6;
  if (lane == 0) sred[wv] = s;
  __syncthreads();
  if (threadIdx.x == 0)
    pqpart[b*CBLK + blockIdx.x] = cadd(cadd(sred[0], sred[1]), cadd(sred[2], sred[3]));
}

__global__ void reduce_pq(const c32* __restrict__ pqpart, c32* __restrict__ pqout,
                          const float* __restrict__ flag)
{
  if (flag[0] == 0.f) return;
  const int lane = threadIdx.x & 63;
  const int b = threadIdx.x >> 6;
  c32 s = make_float2(0.f, 0.f);
  for (int j = lane; j < CBLK; j += 64) s = cadd(s, pqpart[b*CBLK + j]);
  s = wave_reduce_c(s);
  if (lane == 0) pqout[b] = s;
}

// alpha = rr * conj(pq) / |pq|^2 ; x += a p ; r -= a q ; partial sum |r|^2
__global__ __launch_bounds__(256)
void update1(c32* __restrict__ x, c32* __restrict__ r,
             const c32* __restrict__ p, const c32* __restrict__ q,
             const float* __restrict__ rr_i, const c32* __restrict__ pq_i,
             const float* __restrict__ flag, float* __restrict__ part)
{
  if (flag[0] == 0.f) return;
  const int b  = blockIdx.y;
  const int hw = blockIdx.x * 256 + threadIdx.x;
  const float rrv = rr_i[b];
  const c32 pqv = pq_i[b];
  const float den = pqv.x*pqv.x + pqv.y*pqv.y;
  const c32 alpha = make_float2(rrv * pqv.x / den, -rrv * pqv.y / den);
  float acc = 0.f;
  #pragma unroll
  for (int m = 0; m < NM; ++m) {
    const size_t idx = (size_t)(b*NM + m) * NHW + hw;
    c32 pe = p[idx], qe = q[idx];
    c32 xe = cadd(x[idx], cmul(alpha, pe));
    c32 re = csub(r[idx], cmul(alpha, qe));
    x[idx] = xe; r[idx] = re;
    acc += re.x*re.x + re.y*re.y;
  }
  acc = wave_reduce_f(acc);
  __shared__ float sred[4];
  const int lane = threadIdx.x & 63, wv = threadIdx.x >> 6;
  if (lane == 0) sred[wv] = acc;
  __syncthreads();
  if (threadIdx.x == 0) part[b*CBLK + blockIdx.x] = sred[0]+sred[1]+sred[2]+sred[3];
}

__global__ void reduce_rr(const float* __restrict__ part, const float* __restrict__ rr_i,
                          float* __restrict__ rr_n, const float* __restrict__ x0x0,
                          const float* __restrict__ flag_i, float* __restrict__ flag_n)
{
  const int lane = threadIdx.x & 63;
  const int b = threadIdx.x >> 6;
  __shared__ float sred[4];
  __shared__ float sx0[4];
  if (flag_i[0] == 0.f) {
    if (lane == 0) rr_n[b] = rr_i[b];
    if (threadIdx.x == 0) flag_n[0] = 0.f;
    return;
  }
  float s = 0.f;
  for (int j = lane; j < CBLK; j += 64) s += part[b*CBLK + j];
  s = wave_reduce_f(s);
  if (lane == 0) { rr_n[b] = s; sred[b] = s; sx0[b] = x0x0[b]; }
  __syncthreads();
  if (threadIdx.x == 0) {
    float mn = 1e30f;
    #pragma unroll
    for (int bb = 0; bb < NB; ++bb) mn = fminf(mn, sred[bb] / sx0[bb]);
    flag_n[0] = (mn > CG_TOL) ? 1.f : 0.f;
  }
}

// beta = rr_new / rr ; p = r + beta*p
__global__ __launch_bounds__(256)
void update2(c32* __restrict__ p, const c32* __restrict__ r,
             const float* __restrict__ rr_i, const float* __restrict__ rr_n,
             const float* __restrict__ flag)
{
  if (flag[0] == 0.f) return;
  const int b  = blockIdx.y;
  const int hw = blockIdx.x * 256 + threadIdx.x;
  const float beta = rr_n[b] / rr_i[b];
  #pragma unroll
  for (int m = 0; m < NM; ++m) {
    const size_t idx = (size_t)(b*NM + m) * NHW + hw;
    p[idx] = cadd(r[idx], cscale(p[idx], beta));
  }
}

extern "C" void kernel_launch(void* const* d_in, const int* in_sizes, int n_in,
                              void* d_out, int out_size, void* d_ws, size_t ws_size,
                              hipStream_t stream)
{
  const c32*  z   = (const c32*)d_in[0];   // x: (B,M,H,W,2)
  const c32*  y   = (const c32*)d_in[1];   // y: (B,C,H,W,2)
  const c32*  sm  = (const c32*)d_in[2];   // smaps: (B,C,M,H,W,2)
  const float* mk = (const float*)d_in[3]; // mask: (B,C,H,W,1)
  const float* lam= (const float*)d_in[4]; // lambda_a: (1,)
  c32* x = (c32*)d_out;                    // output x lives directly in d_out

  char* base = (char*)d_ws;
  size_t off = 0;
  auto walloc = [&](size_t bytes) -> void* {
    void* ptr = base + off;
    off += (bytes + 255) & ~(size_t)255;
    return ptr;
  };
  c32* buf1   = (c32*)walloc((size_t)NBC * NHW * sizeof(c32));   // 39.3 MB
  c32* buf2   = (c32*)walloc((size_t)NBC * NHW * sizeof(c32));   // 39.3 MB
  c32* rv     = (c32*)walloc((size_t)NB * NM * NHW * sizeof(c32));
  c32* pv     = (c32*)walloc((size_t)NB * NM * NHW * sizeof(c32));
  c32* qv     = (c32*)walloc((size_t)NB * NM * NHW * sizeof(c32));
  c32* pqpart = (c32*)walloc((size_t)NB * CBLK * sizeof(c32));
  c32* pq     = (c32*)walloc((size_t)NITER * NB * sizeof(c32));
  float* x0x0 = (float*)walloc(NB * sizeof(float));
  float* rr   = (float*)walloc((NITER + 1) * NB * sizeof(float));
  float* flags= (float*)walloc((NITER + 1) * sizeof(float));
  float* part1= (float*)walloc((size_t)NB * CBLK * sizeof(float));
  (void)ws_size; (void)in_sizes; (void)n_in; (void)out_size;

  dim3 fgrid(NN / 8, NBC), blk(256);
  dim3 cgrid(CBLK, NB);

  // ---- setup: img(buf1) = unnormalized ifft2(y * mask) ----
  fft_pass<1, 2, 0><<<fgrid, blk, 0, stream>>>(y,    buf2, nullptr, nullptr, mk,      nullptr);
  fft_pass<1, 0, 0><<<fgrid, blk, 0, stream>>>(buf2, buf1, nullptr, nullptr, nullptr, nullptr);
  init_combine<<<cgrid, blk, 0, stream>>>(buf1, sm, z, x, rv, pv, lam, part1);
  reduce_init<<<1, 256, 0, stream>>>(part1, x0x0, rr, flags);

  // ---- 10 CG iterations ----
  for (int i = 0; i < NITER; ++i) {
    const float* fl = flags + i;
    // Mop(p): coil-combine + fwd fft2 + mask + inv fft2 (all unnormalized)
    fft_pass<-1, 1, 0><<<fgrid, blk, 0, stream>>>(nullptr, buf2, pv, sm, nullptr, fl);
    fft_pass<-1, 0, 1><<<fgrid, blk, 0, stream>>>(buf2, buf1, nullptr, nullptr, mk, fl);
    fft_pass< 1, 0, 0><<<fgrid, blk, 0, stream>>>(buf1, buf2, nullptr, nullptr, nullptr, fl);
    fft_pass< 1, 0, 0><<<fgrid, blk, 0, stream>>>(buf2, buf1, nullptr, nullptr, nullptr, fl);
    q_combine<<<cgrid, blk, 0, stream>>>(buf1, sm, pv, qv, lam, fl, pqpart);
    reduce_pq<<<1, 256, 0, stream>>>(pqpart, pq + i*NB, fl);
    update1<<<cgrid, blk, 0, stream>>>(x, rv, pv, qv, rr + i*NB, pq + i*NB, fl, part1);
    reduce_rr<<<1, 256, 0, stream>>>(part1, rr + i*NB, rr + (i+1)*NB, x0x0, fl, flags + (i+1));
    update2<<<cgrid, blk, 0, stream>>>(pv, rv, rr + i*NB, rr + (i+1)*NB, fl);
  }
}